// Round 1
// baseline (350.837 us; speedup 1.0000x reference)
//
#include <hip/hip_runtime.h>
#include <cstdint>

// Problem constants (fixed by setup_inputs): B=4, N=16384, P=1024, C=128
#define BQ_B 4
#define BQ_N 16384
#define BQ_P 1024
#define BQ_C 128
#define NS   64
#define R2   0.04f

// One wave (64 lanes) per query center. 4 waves / 256-thread block.
// Phase 1: ballot-scan ball query -> first NS ascending indices in LDS.
// Phase 2: each lane s owns slot s; writes idx0, grouped_xyz, xyz_feature,
//          then gathers the 128 feature channels.
__global__ __launch_bounds__(256) void qg_kernel(
    const float* __restrict__ xyz,      // (B, N, 3)
    const float* __restrict__ new_xyz,  // (B, P, 3)
    const float* __restrict__ feats,    // (B, C, N)
    float* __restrict__ out)
{
#pragma clang fp contract(off)   // match np reference exactly at the radius boundary
    const int lane   = threadIdx.x & 63;
    const int w      = threadIdx.x >> 6;
    const int center = blockIdx.x * 4 + w;      // b*P + p
    const int b      = center >> 10;            // / P
    const int p      = center & (BQ_P - 1);     // % P

    __shared__ int sidx[4][NS];

    const float cx = new_xyz[center * 3 + 0];
    const float cy = new_xyz[center * 3 + 1];
    const float cz = new_xyz[center * 3 + 2];

    const float* xb = xyz + (size_t)b * BQ_N * 3;

    // ---- Phase 1: ball query (ascending order via ballot prefix) ----
    int count = 0;
    for (int base = 0; base < BQ_N; base += 64) {
        const int i = base + lane;
        const float dx = xb[i * 3 + 0] - cx;
        const float dy = xb[i * 3 + 1] - cy;
        const float dz = xb[i * 3 + 2] - cz;
        const float d2 = dx * dx + dy * dy + dz * dz;  // contract(off): (dx2+dy2)+dz2, IEEE
        const bool hit = d2 < R2;
        const unsigned long long m = __ballot(hit);
        if (hit) {
            const int pos = count + __popcll(m & ((1ull << lane) - 1ull));
            if (pos < NS) sidx[w][pos] = i;
        }
        count += (int)__popcll(m);
        if (count >= NS) break;
    }
    if (count > NS) count = NS;
    __syncthreads();

    const int first = (count > 0) ? sidx[w][0] : BQ_N;
    const int idx0  = (lane < count) ? sidx[w][lane] : first;  // output 3 semantics
    const int gidx  = (lane < count) ? idx0 : BQ_N;            // grouping index (pad -> N)
    const bool real = gidx < BQ_N;

    // Output layout (flat concat, fp32):
    //   region 1: new_features (B,131,P,NS)
    //   region 2: grouped_xyz  (B,3,P,NS)
    //   region 3: idx0         (B,P,NS) stored as float
    const size_t O1 = (size_t)BQ_B * 131 * BQ_P * NS;
    const size_t O2 = O1 + (size_t)BQ_B * 3 * BQ_P * NS;

    out[O2 + (size_t)center * NS + lane] = (float)idx0;

    // xyz channels: grouped_xyz and xyz_feature (channels 0..2 of new_features)
    #pragma unroll
    for (int d = 0; d < 3; ++d) {
        const float c  = (d == 0) ? cx : ((d == 1) ? cy : cz);
        const float pt = real ? xb[gidx * 3 + d] : 1000000.0f;
        const float g  = pt - c;
        out[O1 + ((size_t)(b * 3 + d) * BQ_P + p) * NS + lane] = g;
        const float xf = ((g > 100000.0f) ? 0.0f : g) / 0.2f;  // true division, match ref
        out[((size_t)(b * 131 + d) * BQ_P + p) * NS + lane] = xf;
    }

    // ---- Phase 2: feature gather (channels 3..130 of new_features) ----
    const float* fb = feats + (size_t)b * BQ_C * BQ_N;
    float* o1 = out + ((size_t)(b * 131 + 3) * BQ_P + p) * NS + lane;
    #pragma unroll 8
    for (int c = 0; c < BQ_C; ++c) {
        const float v = real ? fb[(size_t)c * BQ_N + gidx] : 0.0f;
        o1[(size_t)c * (BQ_P * NS)] = v;
    }
}

extern "C" void kernel_launch(void* const* d_in, const int* in_sizes, int n_in,
                              void* d_out, int out_size, void* d_ws, size_t ws_size,
                              hipStream_t stream) {
    const float* xyz      = (const float*)d_in[0];  // (4,16384,3)
    const float* new_xyz  = (const float*)d_in[1];  // (4,1024,3)
    const float* features = (const float*)d_in[2];  // (4,128,16384)
    float* out = (float*)d_out;

    const int n_centers = BQ_B * BQ_P;              // 4096 waves
    dim3 grid(n_centers / 4), block(256);
    qg_kernel<<<grid, block, 0, stream>>>(xyz, new_xyz, features, out);
}

// Round 2
// 298.786 us; speedup vs baseline: 1.1742x; 1.1742x over previous
//
#include <hip/hip_runtime.h>
#include <cstdint>

// Problem constants (fixed by setup_inputs): B=4, N=16384, P=1024, C=128
#define BQ_B 4
#define BQ_N 16384
#define BQ_P 1024
#define BQ_C 128
#define NS   64
#define R2   0.04f

// Output layout (flat concat, fp32):
//   region 1: new_features (B,131,P,NS)
//   region 2: grouped_xyz  (B,3,P,NS)
//   region 3: idx0         (B,P,NS) stored as float
#define O1 ((size_t)BQ_B * 131 * BQ_P * NS)
#define O2 (O1 + (size_t)BQ_B * 3 * BQ_P * NS)

// ws layout: [0, 33554432): features transposed to (B, N, C)
//            [33554432, +1MB): gidx per (center, slot), int32 (BQ_N for pad slots)
#define WS_T_BYTES ((size_t)BQ_B * BQ_N * BQ_C * 4)
#define WS_NEEDED  (WS_T_BYTES + (size_t)BQ_B * BQ_P * NS * 4)

// ---------------- Kernel 1: features (B,C,N) -> ws (B,N,C) ----------------
__global__ __launch_bounds__(256) void transpose_kernel(
    const float* __restrict__ f, float* __restrict__ ft)
{
    // grid: B * 2 * 256 blocks; 64x64 tile each
    const int bid = blockIdx.x;
    const int n0 = (bid & 255) * 64;
    const int c0 = ((bid >> 8) & 1) * 64;
    const int b  = bid >> 9;
    __shared__ float tile[64][65];

    const float* fb = f + ((size_t)b * BQ_C + c0) * BQ_N;
    #pragma unroll
    for (int k = 0; k < 16; ++k) {
        const int cc = k * 4 + (threadIdx.x >> 6);
        const int nn = threadIdx.x & 63;
        tile[cc][nn] = fb[(size_t)cc * BQ_N + n0 + nn];
    }
    __syncthreads();
    float* ob = ft + ((size_t)b * BQ_N + n0) * BQ_C + c0;
    #pragma unroll
    for (int k = 0; k < 16; ++k) {
        const int nn = k * 4 + (threadIdx.x >> 6);
        const int cc = threadIdx.x & 63;
        ob[(size_t)nn * BQ_C + cc] = tile[cc][nn];
    }
}

// ---------------- Kernel 2: ball query + xyz outputs ----------------
// One wave per center; 4 waves/block.
__global__ __launch_bounds__(256) void ballquery_kernel(
    const float* __restrict__ xyz,      // (B, N, 3)
    const float* __restrict__ new_xyz,  // (B, P, 3)
    int* __restrict__ wsIdx,            // (B*P, NS) gather index (BQ_N = pad)
    float* __restrict__ out)
{
#pragma clang fp contract(off)   // match np reference exactly at the radius boundary
    const int lane   = threadIdx.x & 63;
    const int w      = threadIdx.x >> 6;
    const int center = blockIdx.x * 4 + w;
    const int b      = center >> 10;
    const int p      = center & (BQ_P - 1);

    __shared__ int sidx[4][NS];

    const float cx = new_xyz[center * 3 + 0];
    const float cy = new_xyz[center * 3 + 1];
    const float cz = new_xyz[center * 3 + 2];

    const float* xb = xyz + (size_t)b * BQ_N * 3;

    int count = 0;
    for (int base = 0; base < BQ_N; base += 64) {
        const int i = base + lane;
        const float dx = xb[i * 3 + 0] - cx;
        const float dy = xb[i * 3 + 1] - cy;
        const float dz = xb[i * 3 + 2] - cz;
        const float d2 = dx * dx + dy * dy + dz * dz;
        const bool hit = d2 < R2;
        const unsigned long long m = __ballot(hit);
        if (hit) {
            const int pos = count + __popcll(m & ((1ull << lane) - 1ull));
            if (pos < NS) sidx[w][pos] = i;
        }
        count += (int)__popcll(m);
        if (count >= NS) break;
    }
    if (count > NS) count = NS;
    __syncthreads();

    const int first = (count > 0) ? sidx[w][0] : BQ_N;
    const int idx0  = (lane < count) ? sidx[w][lane] : first;
    const int gidx  = (lane < count) ? idx0 : BQ_N;
    const bool real = gidx < BQ_N;

    wsIdx[(size_t)center * NS + lane] = gidx;
    out[O2 + (size_t)center * NS + lane] = (float)idx0;

    #pragma unroll
    for (int d = 0; d < 3; ++d) {
        const float c  = (d == 0) ? cx : ((d == 1) ? cy : cz);
        const float pt = real ? xb[gidx * 3 + d] : 1000000.0f;
        const float g  = pt - c;
        out[O1 + ((size_t)(b * 3 + d) * BQ_P + p) * NS + lane] = g;
        const float xf = ((g > 100000.0f) ? 0.0f : g) / 0.2f;
        out[((size_t)(b * 131 + d) * BQ_P + p) * NS + lane] = xf;
    }
}

// ---------------- Kernel 3: feature gather ----------------
// One block (256 threads) per center. Coalesced 512B reads from transposed
// features, LDS transpose, coalesced channel-major writes.
__global__ __launch_bounds__(256) void gather_kernel(
    const float* __restrict__ ft,       // (B, N, C) transposed
    const int* __restrict__ wsIdx,      // (B*P, NS)
    float* __restrict__ out)
{
    const int center = blockIdx.x;
    const int b = center >> 10;
    const int p = center & (BQ_P - 1);

    __shared__ int   sg[NS];
    __shared__ float tile[NS][BQ_C + 1];

    if (threadIdx.x < NS) sg[threadIdx.x] = wsIdx[(size_t)center * NS + threadIdx.x];
    __syncthreads();

    const float* fb = ft + (size_t)b * BQ_N * BQ_C;
    // gather: 2 slots per iteration; 128 consecutive threads read 512B
    #pragma unroll
    for (int k = 0; k < 32; ++k) {
        const int s = k * 2 + (threadIdx.x >> 7);
        const int c = threadIdx.x & 127;
        const int gi = sg[s];
        tile[s][c] = (gi < BQ_N) ? fb[(size_t)gi * BQ_C + c] : 0.0f;
    }
    __syncthreads();
    // write: 4 channels per iteration; 64 consecutive threads write 256B
    float* ob = out + ((size_t)(b * 131 + 3) * BQ_P + p) * NS;
    #pragma unroll
    for (int k = 0; k < 32; ++k) {
        const int c = k * 4 + (threadIdx.x >> 6);
        const int s = threadIdx.x & 63;
        ob[(size_t)c * (BQ_P * NS) + s] = tile[s][c];
    }
}

// ---------------- Fallback: round-1 monolithic kernel ----------------
__global__ __launch_bounds__(256) void qg_kernel(
    const float* __restrict__ xyz, const float* __restrict__ new_xyz,
    const float* __restrict__ feats, float* __restrict__ out)
{
#pragma clang fp contract(off)
    const int lane   = threadIdx.x & 63;
    const int w      = threadIdx.x >> 6;
    const int center = blockIdx.x * 4 + w;
    const int b      = center >> 10;
    const int p      = center & (BQ_P - 1);
    __shared__ int sidx[4][NS];
    const float cx = new_xyz[center * 3 + 0];
    const float cy = new_xyz[center * 3 + 1];
    const float cz = new_xyz[center * 3 + 2];
    const float* xb = xyz + (size_t)b * BQ_N * 3;
    int count = 0;
    for (int base = 0; base < BQ_N; base += 64) {
        const int i = base + lane;
        const float dx = xb[i * 3 + 0] - cx;
        const float dy = xb[i * 3 + 1] - cy;
        const float dz = xb[i * 3 + 2] - cz;
        const float d2 = dx * dx + dy * dy + dz * dz;
        const bool hit = d2 < R2;
        const unsigned long long m = __ballot(hit);
        if (hit) {
            const int pos = count + __popcll(m & ((1ull << lane) - 1ull));
            if (pos < NS) sidx[w][pos] = i;
        }
        count += (int)__popcll(m);
        if (count >= NS) break;
    }
    if (count > NS) count = NS;
    __syncthreads();
    const int first = (count > 0) ? sidx[w][0] : BQ_N;
    const int idx0  = (lane < count) ? sidx[w][lane] : first;
    const int gidx  = (lane < count) ? idx0 : BQ_N;
    const bool real = gidx < BQ_N;
    out[O2 + (size_t)center * NS + lane] = (float)idx0;
    #pragma unroll
    for (int d = 0; d < 3; ++d) {
        const float c  = (d == 0) ? cx : ((d == 1) ? cy : cz);
        const float pt = real ? xb[gidx * 3 + d] : 1000000.0f;
        const float g  = pt - c;
        out[O1 + ((size_t)(b * 3 + d) * BQ_P + p) * NS + lane] = g;
        const float xf = ((g > 100000.0f) ? 0.0f : g) / 0.2f;
        out[((size_t)(b * 131 + d) * BQ_P + p) * NS + lane] = xf;
    }
    const float* fbt = feats + (size_t)b * BQ_C * BQ_N;
    float* o1 = out + ((size_t)(b * 131 + 3) * BQ_P + p) * NS + lane;
    #pragma unroll 8
    for (int c = 0; c < BQ_C; ++c) {
        const float v = real ? fbt[(size_t)c * BQ_N + gidx] : 0.0f;
        o1[(size_t)c * (BQ_P * NS)] = v;
    }
}

extern "C" void kernel_launch(void* const* d_in, const int* in_sizes, int n_in,
                              void* d_out, int out_size, void* d_ws, size_t ws_size,
                              hipStream_t stream) {
    const float* xyz      = (const float*)d_in[0];  // (4,16384,3)
    const float* new_xyz  = (const float*)d_in[1];  // (4,1024,3)
    const float* features = (const float*)d_in[2];  // (4,128,16384)
    float* out = (float*)d_out;

    if (ws_size >= WS_NEEDED) {
        float* ft    = (float*)d_ws;
        int*   wsIdx = (int*)((char*)d_ws + WS_T_BYTES);
        transpose_kernel<<<dim3(BQ_B * 2 * 256), dim3(256), 0, stream>>>(features, ft);
        ballquery_kernel<<<dim3(BQ_B * BQ_P / 4), dim3(256), 0, stream>>>(xyz, new_xyz, wsIdx, out);
        gather_kernel<<<dim3(BQ_B * BQ_P), dim3(256), 0, stream>>>(ft, wsIdx, out);
    } else {
        qg_kernel<<<dim3(BQ_B * BQ_P / 4), dim3(256), 0, stream>>>(xyz, new_xyz, features, out);
    }
}

// Round 3
// 270.537 us; speedup vs baseline: 1.2968x; 1.1044x over previous
//
#include <hip/hip_runtime.h>
#include <cstdint>

// Problem constants (fixed by setup_inputs): B=4, N=16384, P=1024, C=128
#define BQ_B 4
#define BQ_N 16384
#define BQ_P 1024
#define BQ_C 128
#define NS   64
#define R2   0.04f

// Output layout (flat concat, fp32):
//   region 1: new_features (B,131,P,NS)
//   region 2: grouped_xyz  (B,3,P,NS)
//   region 3: idx0         (B,P,NS) stored as float
#define O1 ((size_t)BQ_B * 131 * BQ_P * NS)
#define O2 (O1 + (size_t)BQ_B * 3 * BQ_P * NS)

// ws: features transposed to (B, N, C)
#define WS_T_BYTES ((size_t)BQ_B * BQ_N * BQ_C * 4)

// ---------------- Kernel 1: features (B,C,N) -> ws (B,N,C) ----------------
__global__ __launch_bounds__(256) void transpose_kernel(
    const float* __restrict__ f, float* __restrict__ ft)
{
    const int bid = blockIdx.x;
    const int n0 = (bid & 255) * 64;
    const int c0 = ((bid >> 8) & 1) * 64;
    const int b  = bid >> 9;
    __shared__ float tile[64][65];

    const float* fb = f + ((size_t)b * BQ_C + c0) * BQ_N;
    #pragma unroll
    for (int k = 0; k < 16; ++k) {
        const int cc = k * 4 + (threadIdx.x >> 6);
        const int nn = threadIdx.x & 63;
        tile[cc][nn] = fb[(size_t)cc * BQ_N + n0 + nn];
    }
    __syncthreads();
    float* ob = ft + ((size_t)b * BQ_N + n0) * BQ_C + c0;
    #pragma unroll
    for (int k = 0; k < 16; ++k) {
        const int nn = k * 4 + (threadIdx.x >> 6);
        const int cc = threadIdx.x & 63;
        ob[(size_t)nn * BQ_C + cc] = tile[cc][nn];
    }
}

// ------------- Kernel 2: fused ball query + grouping, 1 block/center -------------
// Phase 1: 4 waves scan disjoint N/4 segments (2 chunks of 64 per exit check);
//          per-segment ascending hit lists in LDS, merged in segment order.
// Phase 2: coalesced feature gather from transposed ft via LDS tile.
__global__ __launch_bounds__(256) void query_gather_kernel(
    const float* __restrict__ xyz,      // (B, N, 3)
    const float* __restrict__ new_xyz,  // (B, P, 3)
    const float* __restrict__ ft,       // (B, N, C) transposed
    float* __restrict__ out)
{
#pragma clang fp contract(off)   // match np reference exactly at the radius boundary
    const int center = blockIdx.x;
    const int b = center >> 10;
    const int p = center & (BQ_P - 1);
    const int t = threadIdx.x;
    const int lane = t & 63;
    const int w = t >> 6;

    __shared__ int   seg_idx[4][NS];
    __shared__ int   seg_cnt[4];
    __shared__ int   gidx_s[NS];
    __shared__ float tile[NS][BQ_C + 1];

    const float cx = new_xyz[center * 3 + 0];
    const float cy = new_xyz[center * 3 + 1];
    const float cz = new_xyz[center * 3 + 2];
    const float* xb = xyz + (size_t)b * BQ_N * 3;

    // ---- Phase 1: segment scan (wave w owns [w*4096, (w+1)*4096)) ----
    {
        const unsigned long long lmask = (1ull << lane) - 1ull;
        int count = 0;
        const int segbase = w * (BQ_N / 4);
        for (int it = 0; it < 32 && count < NS; ++it) {
            const int i0 = segbase + it * 128 + lane;
            const int i1 = i0 + 64;
            // issue all 6 loads before any ballot
            const float x0 = xb[i0 * 3 + 0], y0 = xb[i0 * 3 + 1], z0 = xb[i0 * 3 + 2];
            const float x1 = xb[i1 * 3 + 0], y1 = xb[i1 * 3 + 1], z1 = xb[i1 * 3 + 2];
            const float dx0 = x0 - cx, dy0 = y0 - cy, dz0 = z0 - cz;
            const float dx1 = x1 - cx, dy1 = y1 - cy, dz1 = z1 - cz;
            const float d20 = dx0 * dx0 + dy0 * dy0 + dz0 * dz0;
            const float d21 = dx1 * dx1 + dy1 * dy1 + dz1 * dz1;
            const bool h0 = d20 < R2;
            const bool h1 = d21 < R2;
            const unsigned long long m0 = __ballot(h0);
            if (h0) {
                const int pos = count + __popcll(m0 & lmask);
                if (pos < NS) seg_idx[w][pos] = i0;
            }
            count += (int)__popcll(m0);
            const unsigned long long m1 = __ballot(h1);
            if (h1) {
                const int pos = count + __popcll(m1 & lmask);
                if (pos < NS) seg_idx[w][pos] = i1;
            }
            count += (int)__popcll(m1);
        }
        if (count > NS) count = NS;
        if (lane == 0) seg_cnt[w] = count;
    }
    __syncthreads();

    // ---- Merge segments (first 64 threads) + xyz/idx outputs ----
    if (t < NS) {
        const int c0 = seg_cnt[0], c1 = seg_cnt[1], c2 = seg_cnt[2], c3 = seg_cnt[3];
        const int o1 = c0, o2 = c0 + c1, o3 = c0 + c1 + c2;
        int total = o3 + c3;
        if (total > NS) total = NS;

        int first = BQ_N;
        if (c0 > 0) first = seg_idx[0][0];
        else if (c1 > 0) first = seg_idx[1][0];
        else if (c2 > 0) first = seg_idx[2][0];
        else if (c3 > 0) first = seg_idx[3][0];

        int v = BQ_N;
        if (t < total) {
            if (t < o1)      v = seg_idx[0][t];
            else if (t < o2) v = seg_idx[1][t - o1];
            else if (t < o3) v = seg_idx[2][t - o2];
            else             v = seg_idx[3][t - o3];
        }
        const int idx0 = (t < total) ? v : first;
        const int gidx = (t < total) ? v : BQ_N;
        const bool real = gidx < BQ_N;
        gidx_s[t] = gidx;

        out[O2 + (size_t)center * NS + t] = (float)idx0;

        #pragma unroll
        for (int d = 0; d < 3; ++d) {
            const float c = (d == 0) ? cx : ((d == 1) ? cy : cz);
            const float pt = real ? xb[gidx * 3 + d] : 1000000.0f;
            const float g = pt - c;
            out[O1 + ((size_t)(b * 3 + d) * BQ_P + p) * NS + t] = g;
            const float xf = ((g > 100000.0f) ? 0.0f : g) / 0.2f;
            out[((size_t)(b * 131 + d) * BQ_P + p) * NS + t] = xf;
        }
    }
    __syncthreads();

    // ---- Phase 2: feature gather (channels 3..130) ----
    const float* fb = ft + (size_t)b * BQ_N * BQ_C;
    #pragma unroll
    for (int k = 0; k < 32; ++k) {
        const int s = k * 2 + (t >> 7);
        const int c = t & 127;
        const int gi = gidx_s[s];
        tile[s][c] = (gi < BQ_N) ? fb[(size_t)gi * BQ_C + c] : 0.0f;
    }
    __syncthreads();
    float* ob = out + ((size_t)(b * 131 + 3) * BQ_P + p) * NS;
    #pragma unroll
    for (int k = 0; k < 32; ++k) {
        const int c = k * 4 + (t >> 6);
        const int s = t & 63;
        ob[(size_t)c * (BQ_P * NS) + s] = tile[s][c];
    }
}

extern "C" void kernel_launch(void* const* d_in, const int* in_sizes, int n_in,
                              void* d_out, int out_size, void* d_ws, size_t ws_size,
                              hipStream_t stream) {
    const float* xyz      = (const float*)d_in[0];  // (4,16384,3)
    const float* new_xyz  = (const float*)d_in[1];  // (4,1024,3)
    const float* features = (const float*)d_in[2];  // (4,128,16384)
    float* out = (float*)d_out;
    float* ft  = (float*)d_ws;

    transpose_kernel<<<dim3(BQ_B * 2 * 256), dim3(256), 0, stream>>>(features, ft);
    query_gather_kernel<<<dim3(BQ_B * BQ_P), dim3(256), 0, stream>>>(xyz, new_xyz, ft, out);
}

// Round 4
// 234.592 us; speedup vs baseline: 1.4955x; 1.1532x over previous
//
#include <hip/hip_runtime.h>
#include <cstdint>

// Problem constants (fixed by setup_inputs): B=4, N=16384, P=1024, C=128
#define BQ_B 4
#define BQ_N 16384
#define BQ_P 1024
#define BQ_C 128
#define NS   64
#define R2   0.04f

// Output layout (flat concat, fp32):
//   region 1: new_features (B,131,P,NS)
//   region 2: grouped_xyz  (B,3,P,NS)
//   region 3: idx0         (B,P,NS) stored as float
#define O1 ((size_t)BQ_B * 131 * BQ_P * NS)
#define O2 (O1 + (size_t)BQ_B * 3 * BQ_P * NS)

// ws: features transposed to (B, N, C)
#define WS_T_BYTES ((size_t)BQ_B * BQ_N * BQ_C * 4)

// ---------------- Kernel 1: features (B,C,N) -> ws (B,N,C) ----------------
__global__ __launch_bounds__(256) void transpose_kernel(
    const float* __restrict__ f, float* __restrict__ ft)
{
    const int bid = blockIdx.x;
    const int n0 = (bid & 255) * 64;
    const int c0 = ((bid >> 8) & 1) * 64;
    const int b  = bid >> 9;
    __shared__ float tile[64][65];

    const float* fb = f + ((size_t)b * BQ_C + c0) * BQ_N;
    #pragma unroll
    for (int k = 0; k < 16; ++k) {
        const int cc = k * 4 + (threadIdx.x >> 6);
        const int nn = threadIdx.x & 63;
        tile[cc][nn] = fb[(size_t)cc * BQ_N + n0 + nn];
    }
    __syncthreads();
    float* ob = ft + ((size_t)b * BQ_N + n0) * BQ_C + c0;
    #pragma unroll
    for (int k = 0; k < 16; ++k) {
        const int nn = k * 4 + (threadIdx.x >> 6);
        const int cc = threadIdx.x & 63;
        ob[(size_t)nn * BQ_C + cc] = tile[cc][nn];
    }
}

// ------------- Kernel 2: fused ball query + grouping, 1 block/center -------------
// 512 threads = 8 waves. Round-based cooperative scan: per round, the block
// evaluates 4096 points (8 waves x 8 chunks of 64, all loads independent),
// stores per-chunk hit masks to LDS; wave 0 prefix-sums the 64 chunk counts;
// all waves scatter ranked hit indices. Exit when >= NS hits found.
// Then coalesced feature gather from transposed ft via LDS tile.
__global__ __launch_bounds__(512, 8) void query_gather_kernel(
    const float* __restrict__ xyz,      // (B, N, 3)
    const float* __restrict__ new_xyz,  // (B, P, 3)
    const float* __restrict__ ft,       // (B, N, C) transposed
    float* __restrict__ out)
{
#pragma clang fp contract(off)   // match np reference exactly at the radius boundary
    const int center = blockIdx.x;
    const int b = center >> 10;
    const int p = center & (BQ_P - 1);
    const int t = threadIdx.x;
    const int lane = t & 63;
    const int w = t >> 6;               // wave 0..7

    __shared__ unsigned long long smask[64];   // per-chunk hit masks (this round)
    __shared__ int   sprefix[64];              // exclusive rank base per chunk
    __shared__ int   s_total;                  // total hits so far
    __shared__ int   lds_idx[NS];              // first NS ascending hit indices
    __shared__ int   gidx_s[NS];               // gather index per slot (BQ_N = pad)
    __shared__ float tile[NS][BQ_C + 1];

    const float cx = new_xyz[center * 3 + 0];
    const float cy = new_xyz[center * 3 + 1];
    const float cz = new_xyz[center * 3 + 2];
    const float* xb = xyz + (size_t)b * BQ_N * 3;

    int total = 0;
    const unsigned long long lmask = (1ull << lane) - 1ull;

    for (int round = 0; round < 4; ++round) {
        const int rbase = round * 4096;
        // ---- masks for my 8 chunks (no dependent chain; loads all independent) ----
        #pragma unroll
        for (int k = 0; k < 8; ++k) {
            const int j = w * 8 + k;
            const int i = rbase + j * 64 + lane;
            const float dx = xb[i * 3 + 0] - cx;
            const float dy = xb[i * 3 + 1] - cy;
            const float dz = xb[i * 3 + 2] - cz;
            const float d2 = dx * dx + dy * dy + dz * dz;
            const unsigned long long m = __ballot(d2 < R2);
            if (lane == 0) smask[j] = m;
        }
        __syncthreads();   // barrier A: all masks visible

        // ---- wave 0: prefix-sum the 64 chunk counts ----
        if (w == 0) {
            const unsigned long long mm = smask[lane];
            const int cnt = (int)__popcll(mm);
            int x = cnt;
            #pragma unroll
            for (int d = 1; d < 64; d <<= 1) {
                const int y = __shfl_up(x, d, 64);
                if (lane >= d) x += y;
            }
            sprefix[lane] = total + (x - cnt);      // exclusive prefix + base
            if (lane == 63) s_total = total + x;
        }
        __syncthreads();   // barrier B: sprefix/s_total visible

        // ---- scatter ranked indices for my chunks ----
        const int new_total = s_total;
        #pragma unroll
        for (int k = 0; k < 8; ++k) {
            const int j = w * 8 + k;
            const unsigned long long m = smask[j];
            const int baser = sprefix[j];
            if (baser < NS && ((m >> lane) & 1ull)) {
                const int r = baser + (int)__popcll(m & lmask);
                if (r < NS) lds_idx[r] = rbase + j * 64 + lane;
            }
        }
        total = new_total;
        if (new_total >= NS) break;
    }
    __syncthreads();

    // ---- slot assignment + xyz/idx outputs (threads 0..63) ----
    if (t < NS) {
        const int tt = (total > NS) ? NS : total;
        const int first = (total > 0) ? lds_idx[0] : BQ_N;
        const int v = (t < tt) ? lds_idx[t] : BQ_N;
        const int idx0 = (t < tt) ? v : first;
        const int gidx = v;                 // BQ_N for pad slots
        const bool real = gidx < BQ_N;
        gidx_s[t] = gidx;

        out[O2 + (size_t)center * NS + t] = (float)idx0;

        #pragma unroll
        for (int d = 0; d < 3; ++d) {
            const float c = (d == 0) ? cx : ((d == 1) ? cy : cz);
            const float pt = real ? xb[gidx * 3 + d] : 1000000.0f;
            const float g = pt - c;
            out[O1 + ((size_t)(b * 3 + d) * BQ_P + p) * NS + t] = g;
            const float xf = ((g > 100000.0f) ? 0.0f : g) / 0.2f;
            out[((size_t)(b * 131 + d) * BQ_P + p) * NS + t] = xf;
        }
    }
    __syncthreads();

    // ---- feature gather (channels 3..130) ----
    const float* fb = ft + (size_t)b * BQ_N * BQ_C;
    #pragma unroll
    for (int k = 0; k < 16; ++k) {
        const int s = k * 4 + (t >> 7);
        const int c = t & 127;
        const int gi = gidx_s[s];
        tile[s][c] = (gi < BQ_N) ? fb[(size_t)gi * BQ_C + c] : 0.0f;
    }
    __syncthreads();
    float* ob = out + ((size_t)(b * 131 + 3) * BQ_P + p) * NS;
    #pragma unroll
    for (int k = 0; k < 16; ++k) {
        const int c = k * 8 + (t >> 6);
        const int s = t & 63;
        ob[(size_t)c * (BQ_P * NS) + s] = tile[s][c];
    }
}

extern "C" void kernel_launch(void* const* d_in, const int* in_sizes, int n_in,
                              void* d_out, int out_size, void* d_ws, size_t ws_size,
                              hipStream_t stream) {
    const float* xyz      = (const float*)d_in[0];  // (4,16384,3)
    const float* new_xyz  = (const float*)d_in[1];  // (4,1024,3)
    const float* features = (const float*)d_in[2];  // (4,128,16384)
    float* out = (float*)d_out;
    float* ft  = (float*)d_ws;

    transpose_kernel<<<dim3(BQ_B * 2 * 256), dim3(256), 0, stream>>>(features, ft);
    query_gather_kernel<<<dim3(BQ_B * BQ_P), dim3(512), 0, stream>>>(xyz, new_xyz, ft, out);
}